// Round 7
// baseline (537.760 us; speedup 1.0000x reference)
//
#include <hip/hip_runtime.h>
#include <hip/hip_bf16.h>
#include <cmath>

#define T_STEPS 16
#define BATCH   512
#define N_IN    3072
#define S1      256
#define S2      256
#define S3      128
#define NEXP    8
#define M_ROWS  (T_STEPS * BATCH)   // 8192
#define MT_ALL  (M_ROWS / 32)       // 256 m-tiles

typedef int v4i  __attribute__((ext_vector_type(4)));
typedef int v16i __attribute__((ext_vector_type(16)));
typedef unsigned long long u64;
typedef unsigned int uint32;
typedef unsigned short u16;

// ---------------------------------------------------------------------------
// bit->byte unpack: 16 bits -> 16 i8 (0/1). mul-free: per nibble
// x*(1+2^7)(1+2^14) spread + mask. ~16 VALU per 16 bytes (near floor).
// R4/R5: this VALU is also latency cover -- only shave with cover in place.
// ---------------------------------------------------------------------------
__device__ __forceinline__ v4i unpack16_bits(uint32 w16)
{
    v4i d;
    #pragma unroll
    for (int c = 0; c < 4; ++c) {
        uint32 x = (w16 >> (4 * c)) & 0xFu;
        x = x + (x << 7);
        x = x + (x << 14);
        d[c] = (int)(x & 0x01010101u);
    }
    return d;
}

// ---------------------------------------------------------------------------
// Weight digitize -> MFMA fragment tiles. B-row gr = o*32 + e*4 + limb.
// Bf[kb][nt=o][lane16][16], lane16 = (e*4+limb) + 32*qd, k = kb*32+qd*16+byte.
// ---------------------------------------------------------------------------
template<int S, int K>
__device__ __forceinline__ void digitize_chunk(
    const float* __restrict__ W, char* __restrict__ Bf, int t)
{
    int lane16 = t & 63;
    int o  = (t >> 6) & (S - 1);
    int kb = t >> ((S == 256) ? 14 : 13);
    int r  = lane16 & 31;
    int qd = lane16 >> 5;
    int e    = r >> 2;
    int limb = r & 3;
    int k0 = kb * 32 + qd * 16;

    const float4* Wp = (const float4*)(W + ((size_t)e * S + o) * K + k0);
    char out[16];
    #pragma unroll
    for (int f4 = 0; f4 < 4; ++f4) {
        float4 w = Wp[f4];
        float ws[4] = {w.x, w.y, w.z, w.w};
        #pragma unroll
        for (int c = 0; c < 4; ++c) {
            long long q = llrint((double)ws[c] * 4294967296.0);
            int d = 0;
            #pragma unroll
            for (int l = 0; l < 4; ++l) {
                int dl = (int)((q + 128) & 255) - 128;
                q = (q - dl) >> 8;
                if (l == limb) d = dl;
            }
            out[f4 * 4 + c] = (char)d;
        }
    }
    *(v4i*)(Bf + (size_t)t * 16) = *(v4i*)out;
}

// ---------------------------------------------------------------------------
// Single prep dispatch = pack_x_bits + digitize W1/W2/W3.
// ---------------------------------------------------------------------------
__global__ __launch_bounds__(256) void prep(
    const float* __restrict__ x,  const float* __restrict__ W1,
    const float* __restrict__ W2, const float* __restrict__ W3,
    u64* __restrict__ bitsT, char* __restrict__ B1f,
    char* __restrict__ B2f,  char* __restrict__ B3f)
{
    const int bid = blockIdx.x;
    const int tid = threadIdx.x;
    if (bid < 98304) {
        int gid = bid * 256 + tid;
        float v = x[gid];
        u64 m = __ballot(v >= 0.5f);
        if ((tid & 63) == 0) {
            int tb = gid / N_IN;                 // t*512 + b
            int k  = gid - tb * N_IN;
            int t  = tb >> 9;
            int b  = tb & 511;
            bitsT[(size_t)(k >> 6) * M_ROWS + (b * 16 + t)] = m;
        }
    } else if (bid < 98304 + 6144) {
        digitize_chunk<S1, N_IN>(W1, B1f, (bid - 98304) * 256 + tid);
    } else if (bid < 98304 + 6144 + 512) {
        digitize_chunk<S2, S1>(W2, B2f, (bid - 98304 - 6144) * 256 + tid);
    } else {
        digitize_chunk<S3, S2>(W3, B3f, (bid - 98304 - 6656) * 256 + tid);
    }
}

// ---------------------------------------------------------------------------
// Fused expert-GEMM + limb recombine + LIF + gated combine + mean.
// R7 = R6's proven structure (64x64 wave tile, distance-2 triple-buffer +
// setprio cover on the bits path) with ALL load addressing strength-reduced
// to SALU: uniform loop-carried base pointers (SGPR, stepped by s_add) +
// per-lane int voffsets computed once (saddr-form global loads). A-subwords
// are read as ushort directly (imm picks the (ks,qd) 16-bit field), killing
// the u64 extract/shift VALU. Target: VALU/body ~190 -> ~80 inst, unpack
// becomes the only VALU stream beside MFMA.
// ---------------------------------------------------------------------------
template<int K, int S, int SHIFT, bool ABITS, bool WRITEC, int NBLK, int MINW>
__global__ __launch_bounds__(256, MINW) void fused_stage(
    const void* __restrict__ Ap, const char* __restrict__ Bf,
    const float* __restrict__ g, char* __restrict__ Cf,
    float* __restrict__ Mean)
{
    constexpr int KI = K / 64;
    constexpr int NT = S;                    // 32-row n-tiles in Bf
    constexpr int NS = NBLK / 8;
    constexpr int BSTEP = 2 * NT * 1024;     // B bytes per body (2 kb)
    static_assert(M_ROWS / 256 == 32, "mblk count must be 32");
    __shared__ double hs[256][16];           // 32 KB

    const int tid  = threadIdx.x;
    const int lane = tid & 63;
    const int w    = tid >> 6;
    const int col  = lane & 31;
    const int qd   = lane >> 5;
    const int wm   = w * 64;

    // mblk-major XCD mapping: co-resident blocks share one B slab.
    const int id    = blockIdx.x;
    const int xcd   = id & 7;
    const int inner = id >> 3;
    const int nblk  = xcd * NS + (inner >> 5);
    const int mblk  = inner & 31;
    const int m0    = mblk * 256;

    const int nt0 = nblk * 2;

    // uniform B base (SGPR) + per-lane voffsets; imm 1024 selects jj.
    const char* Bu  = Bf + (size_t)nt0 * 1024;
    const int   vB0 = lane * 16;
    const int   vB1 = lane * 16 + NT * 1024;

    v16i acc[2][2];
    #pragma unroll
    for (int i = 0; i < 2; ++i)
        #pragma unroll
        for (int j = 0; j < 2; ++j)
            #pragma unroll
            for (int r = 0; r < 16; ++r) acc[i][j][r] = 0;

    auto ldB = [&](const char* bu, int voff, int imm) -> v4i {
        return *(const v4i*)(bu + voff + imm);
    };

    if constexpr (ABITS) {
        static_assert(!ABITS || KI % 3 == 0, "bits path wants KI % 3 == 0");
        // A bits as u16 subwords: byte addr = m*8 + it*65536 + (ks*2+qd)*2.
        // uniform: Au = Ap + m0*8 (stepped); voffset vA = (wm+col)*8 + qd*2;
        // imm: ks*4 (+256 for the second m-tile, row+32).
        const char* Au = (const char*)Ap + (size_t)m0 * 8;
        const int   vA = (wm + col) * 8 + qd * 2;

        auto ldA = [&](const char* au, int imm) -> uint32 {
            return (uint32)*(const u16*)(au + vA + imm);
        };

        uint32 ab[3][4];   // [buf][mt*2+ks]
        v4i    Bb[3][4];   // [buf][ks*2+jj]

        // preload bodies 0,1 (distance-2)
        #pragma unroll
        for (int s = 0; s < 2; ++s) {
            const char* au = Au + s * 65536;
            const char* bu = Bu + s * BSTEP;
            ab[s][0] = ldA(au, 0);
            ab[s][1] = ldA(au, 4);
            ab[s][2] = ldA(au, 256);
            ab[s][3] = ldA(au, 260);
            Bb[s][0] = ldB(bu, vB0, 0);
            Bb[s][1] = ldB(bu, vB0, 1024);
            Bb[s][2] = ldB(bu, vB1, 0);
            Bb[s][3] = ldB(bu, vB1, 1024);
        }
        // loop-carried uniform prefetch pointers (SALU-stepped)
        const char* Auf = Au + 2 * 65536;
        const char* Buf = Bu + 2 * BSTEP;

        auto body = [&](int cur, int pf) {
            ab[pf][0] = ldA(Auf, 0);
            ab[pf][1] = ldA(Auf, 4);
            ab[pf][2] = ldA(Auf, 256);
            ab[pf][3] = ldA(Auf, 260);
            Bb[pf][0] = ldB(Buf, vB0, 0);
            Bb[pf][1] = ldB(Buf, vB0, 1024);
            Bb[pf][2] = ldB(Buf, vB1, 0);
            Bb[pf][3] = ldB(Buf, vB1, 1024);
            Auf += 65536;
            Buf += BSTEP;
            __builtin_amdgcn_s_setprio(1);
            #pragma unroll
            for (int ks = 0; ks < 2; ++ks) {
                v4i af0 = unpack16_bits(ab[cur][ks]);
                v4i af1 = unpack16_bits(ab[cur][2 + ks]);
                #pragma unroll
                for (int jj = 0; jj < 2; ++jj) {
                    acc[0][jj] = __builtin_amdgcn_mfma_i32_32x32x32_i8(af0, Bb[cur][ks*2+jj], acc[0][jj], 0,0,0);
                    acc[1][jj] = __builtin_amdgcn_mfma_i32_32x32x32_i8(af1, Bb[cur][ks*2+jj], acc[1][jj], 0,0,0);
                }
            }
            __builtin_amdgcn_s_setprio(0);
        };
        for (int it = 0; it < KI; it += 3) {
            body(0, 2);
            body(1, 0);
            body(2, 1);
        }
    } else {
        static_assert(ABITS || KI % 2 == 0, "frag path wants even KI");
        // A frag: byte = (mt0+ii)*1024 + kb*MT_ALL*1024 + lane*16 with
        // mt0 = (m0+wm)>>5. uniform: Apu = Ap + (m0>>5)*1024 (stepped);
        // voffsets vA0/vA1 carry (wm>>5)*1024 + lane*16 (+256K for kb odd).
        const char* Apu = (const char*)Ap + (size_t)(m0 >> 5) * 1024;
        const int   vA0 = (w * 2) * 1024 + lane * 16;
        const int   vA1 = vA0 + MT_ALL * 1024;

        auto ldA = [&](const char* au, int voff, int imm) -> v4i {
            return *(const v4i*)(au + voff + imm);
        };

        v4i Ab[2][4];   // [buf][ks*2+ii]
        v4i Bb[2][4];

        // preload body 0 (distance-1; KI is tiny here)
        Ab[0][0] = ldA(Apu, vA0, 0);
        Ab[0][1] = ldA(Apu, vA0, 1024);
        Ab[0][2] = ldA(Apu, vA1, 0);
        Ab[0][3] = ldA(Apu, vA1, 1024);
        Bb[0][0] = ldB(Bu, vB0, 0);
        Bb[0][1] = ldB(Bu, vB0, 1024);
        Bb[0][2] = ldB(Bu, vB1, 0);
        Bb[0][3] = ldB(Bu, vB1, 1024);

        const char* Auf = Apu + (size_t)2 * MT_ALL * 1024;
        const char* Buf = Bu + BSTEP;

        auto body = [&](int cur, int pf) {
            Ab[pf][0] = ldA(Auf, vA0, 0);
            Ab[pf][1] = ldA(Auf, vA0, 1024);
            Ab[pf][2] = ldA(Auf, vA1, 0);
            Ab[pf][3] = ldA(Auf, vA1, 1024);
            Bb[pf][0] = ldB(Buf, vB0, 0);
            Bb[pf][1] = ldB(Buf, vB0, 1024);
            Bb[pf][2] = ldB(Buf, vB1, 0);
            Bb[pf][3] = ldB(Buf, vB1, 1024);
            Auf += (size_t)2 * MT_ALL * 1024;
            Buf += BSTEP;
            #pragma unroll
            for (int ks = 0; ks < 2; ++ks)
                #pragma unroll
                for (int jj = 0; jj < 2; ++jj) {
                    acc[0][jj] = __builtin_amdgcn_mfma_i32_32x32x32_i8(Ab[cur][ks*2+0], Bb[cur][ks*2+jj], acc[0][jj], 0,0,0);
                    acc[1][jj] = __builtin_amdgcn_mfma_i32_32x32x32_i8(Ab[cur][ks*2+1], Bb[cur][ks*2+jj], acc[1][jj], 0,0,0);
                }
        };
        for (int it = 0; it < KI; it += 2) {
            body(0, 1);
            body(1, 0);
        }
    }

    // ---- limb recombine (exact): int pair-combine then one f64 fma ----
    const double sbase = 1.0 / (double)(1ll << SHIFT);
    #pragma unroll
    for (int j = 0; j < 2; ++j) {
        const int oe = j * 8 + (col >> 2);            // o_loc*8 + e
        #pragma unroll
        for (int i = 0; i < 2; ++i) {
            #pragma unroll
            for (int reg = 0; reg < 16; ++reg) {
                int a = acc[i][j][reg];
                int s01 = a + (__shfl_xor(a, 1) << 8);
                int s23 = __shfl_xor(s01, 2);
                double d = ((double)s01 + 65536.0 * (double)s23) * sbase;
                if ((col & 3) == 0) {
                    int m = wm + i * 32 + (reg & 3) + 8 * (reg >> 2) + 4 * qd;
                    hs[m][oe] = d;
                }
            }
        }
    }
    __syncthreads();

    // ---- LIF scan: thread = (b_loc = tid>>4, o_loc = (tid>>3)&1, e = tid&7)
    const int b_loc  = tid >> 4;
    const int o_loc  = (tid >> 3) & 1;
    const int e      = tid & 7;
    const int oe     = o_loc * 8 + e;
    const float ge   = g[e];
    const int bg = mblk * 16 + b_loc;
    const int og = nblk * 2 + o_loc;

    // fragment-tile write coords for counts (k = og of this stage)
    const int kb_a   = og >> 5;
    const int qd_a   = (og >> 4) & 1;
    const int byte_a = og & 15;

    double v = 0.0;
    float gacc = 0.0f;
    #pragma unroll
    for (int t = 0; t < T_STEPS; ++t) {
        double h  = hs[b_loc * 16 + t][oe];
        double vv = v * 0.95 + h;
        int spk = (vv >= 1.0) ? 1 : 0;
        v = vv - (double)spk;
        float gs = ge * (float)spk;
        gs += __shfl_xor(gs, 1);
        gs += __shfl_xor(gs, 2);
        gs += __shfl_xor(gs, 4);
        gacc += gs;
        if (WRITEC) {
            int cnt = spk;
            cnt += __shfl_xor(cnt, 1);
            cnt += __shfl_xor(cnt, 2);
            cnt += __shfl_xor(cnt, 4);
            if (e == 0) {
                int mp = bg * 16 + t;
                int lane_a = (mp & 31) + 32 * qd_a;
                Cf[(((size_t)kb_a * MT_ALL + (mp >> 5)) * 64 + lane_a) * 16 + byte_a]
                    = (char)cnt;
            }
        }
    }
    if (e == 0) Mean[(size_t)bg * S + og] = gacc * 0.0625f;
}

// ---------------------------------------------------------------------------
// ws layout (bytes), buffers padded for clamp-free distance-2 prefetch:
//   AbitsT @ 0          : 3 MB + 1 MB pad
//   B1f    @ 4194304    : 24 MB + ~3 MB pad
//   B2f    @ 31457280   :  2 MB + 1 MB pad
//   B3f    @ 34603008   :  1 MB + 512 KB pad
//   c1f    @ 36175872   :  2 MB + 1 MB pad
//   c2f    @ 39321600   :  2 MB + ~560 KB pad  -> end 41943040 (40 MB)
// ---------------------------------------------------------------------------
extern "C" void kernel_launch(void* const* d_in, const int* in_sizes, int n_in,
                              void* d_out, int out_size, void* d_ws, size_t ws_size,
                              hipStream_t stream) {
    const float* x  = (const float*)d_in[0];
    const float* W1 = (const float*)d_in[1];
    const float* W2 = (const float*)d_in[2];
    const float* W3 = (const float*)d_in[3];
    const float* g1 = (const float*)d_in[4];
    const float* g2 = (const float*)d_in[5];
    const float* g3 = (const float*)d_in[6];
    float* out = (float*)d_out;

    char* ws = (char*)d_ws;
    u64*  AbitsT = (u64*)ws;
    char* B1f    = ws + 4194304ull;
    char* B2f    = ws + 31457280ull;
    char* B3f    = ws + 34603008ull;
    char* c1f    = ws + 36175872ull;
    char* c2f    = ws + 39321600ull;

    dim3 blk(256);

    // --- single precompute dispatch ---
    prep<<<98304 + 6144 + 512 + 256, blk, 0, stream>>>(
        x, W1, W2, W3, AbitsT, B1f, B2f, B3f);

    // --- three fused GEMM+LIF stages, mblk-major XCD-swizzled 1-D grids ---
    fused_stage<N_IN, S1, 32, true,  true,  128, 3><<<32 * 128, blk, 0, stream>>>(
        AbitsT, B1f, g1, c1f, out);
    fused_stage<S1,   S2, 35, false, true,  128, 3><<<32 * 128, blk, 0, stream>>>(
        c1f, B2f, g2, c2f, out + BATCH * S1);
    fused_stage<S2,   S3, 35, false, false, 64, 3><<<32 * 64, blk, 0, stream>>>(
        c2f, B3f, g3, nullptr, out + BATCH * (S1 + S2));
}

// Round 8
// 489.446 us; speedup vs baseline: 1.0987x; 1.0987x over previous
//
#include <hip/hip_runtime.h>
#include <hip/hip_bf16.h>
#include <cmath>

#define T_STEPS 16
#define BATCH   512
#define N_IN    3072
#define S1      256
#define S2      256
#define S3      128
#define NEXP    8
#define M_ROWS  (T_STEPS * BATCH)   // 8192
#define MT_ALL  (M_ROWS / 32)       // 256 m-tiles

typedef int v4i  __attribute__((ext_vector_type(4)));
typedef int v16i __attribute__((ext_vector_type(16)));
typedef unsigned long long u64;
typedef unsigned int uint32;

// ---------------------------------------------------------------------------
// bit->byte unpack: 16 bits -> 16 i8 (0/1). mul-free spread.
// ---------------------------------------------------------------------------
__device__ __forceinline__ v4i unpack16_bits(uint32 w16)
{
    v4i d;
    #pragma unroll
    for (int c = 0; c < 4; ++c) {
        uint32 x = (w16 >> (4 * c)) & 0xFu;
        x = x + (x << 7);
        x = x + (x << 14);
        d[c] = (int)(x & 0x01010101u);
    }
    return d;
}

// ---------------------------------------------------------------------------
// 4-limb weight digitize (stages 2/3). B-row gr = o*32 + e*4 + limb.
// ---------------------------------------------------------------------------
template<int S, int K>
__device__ __forceinline__ void digitize_chunk(
    const float* __restrict__ W, char* __restrict__ Bf, int t)
{
    int lane16 = t & 63;
    int o  = (t >> 6) & (S - 1);
    int kb = t >> ((S == 256) ? 14 : 13);
    int r  = lane16 & 31;
    int qd = lane16 >> 5;
    int e    = r >> 2;
    int limb = r & 3;
    int k0 = kb * 32 + qd * 16;

    const float4* Wp = (const float4*)(W + ((size_t)e * S + o) * K + k0);
    char out[16];
    #pragma unroll
    for (int f4 = 0; f4 < 4; ++f4) {
        float4 w = Wp[f4];
        float ws[4] = {w.x, w.y, w.z, w.w};
        #pragma unroll
        for (int c = 0; c < 4; ++c) {
            long long q = llrint((double)ws[c] * 4294967296.0);
            int d = 0;
            #pragma unroll
            for (int l = 0; l < 4; ++l) {
                int dl = (int)((q + 128) & 255) - 128;
                q = (q - dl) >> 8;
                if (l == limb) d = dl;
            }
            out[f4 * 4 + c] = (char)d;
        }
    }
    *(v4i*)(Bf + (size_t)t * 16) = *(v4i*)out;
}

// ---------------------------------------------------------------------------
// prep: pack x bits + 3-limb digitize W1 + 4-limb digitize W2/W3.
// R8: W1 goes 3-limb (q = llrint(w*2^24), |q|<2^23 fits 3 signed bytes;
// decomposition exact). Rows gr = o*24 + e*3 + limb, 6144 rows = 192 tiles.
// ---------------------------------------------------------------------------
__global__ __launch_bounds__(256) void prep(
    const float* __restrict__ x,  const float* __restrict__ W1,
    const float* __restrict__ W2, const float* __restrict__ W3,
    u64* __restrict__ bitsT, char* __restrict__ B1f,
    char* __restrict__ B2f,  char* __restrict__ B3f)
{
    const int bid = blockIdx.x;
    const int tid = threadIdx.x;
    if (bid < 98304) {
        int gid = bid * 256 + tid;
        float v = x[gid];
        u64 m = __ballot(v >= 0.5f);
        if ((tid & 63) == 0) {
            int tb = gid / N_IN;                 // t*512 + b
            int k  = gid - tb * N_IN;
            int t  = tb >> 9;
            int b  = tb & 511;
            bitsT[(size_t)(k >> 6) * M_ROWS + (b * 16 + t)] = m;
        }
    } else if (bid < 98304 + 4608) {
        // W1 3-limb: chunks = 96 kb * 192 tiles * 64 l16
        int t    = (bid - 98304) * 256 + tid;
        int l16  = t & 63;
        int tt   = t >> 6;               // kb*192 + tile
        int tile = tt % 192;
        int kb   = tt / 192;
        int gr   = tile * 32 + (l16 & 31);
        int qd   = l16 >> 5;
        int o    = gr / 24;
        int rem  = gr - o * 24;
        int e    = rem / 3;
        int limb = rem - e * 3;
        int k0   = kb * 32 + qd * 16;
        const float4* Wp = (const float4*)(W1 + ((size_t)e * S1 + o) * N_IN + k0);
        char out[16];
        #pragma unroll
        for (int f4 = 0; f4 < 4; ++f4) {
            float4 w = Wp[f4];
            float ws[4] = {w.x, w.y, w.z, w.w};
            #pragma unroll
            for (int c = 0; c < 4; ++c) {
                long long q = llrint((double)ws[c] * 16777216.0);
                int d0 = (int)((q + 128) & 255) - 128;
                long long q1 = (q - d0) >> 8;
                int d1 = (int)((q1 + 128) & 255) - 128;
                int d2 = (int)((q1 - d1) >> 8);
                int d  = (limb == 0) ? d0 : ((limb == 1) ? d1 : d2);
                out[f4 * 4 + c] = (char)d;
            }
        }
        *(v4i*)(B1f + (size_t)t * 16) = *(v4i*)out;
    } else if (bid < 98304 + 4608 + 512) {
        digitize_chunk<S2, S1>(W2, B2f, (bid - 98304 - 4608) * 256 + tid);
    } else {
        digitize_chunk<S3, S2>(W3, B3f, (bid - 98304 - 4608 - 512) * 256 + tid);
    }
}

// ---------------------------------------------------------------------------
// R8 stage 1: 3-limb GEMM + LDS-i64 limb accumulate + LIF.
// Block 128m x 96n; wave tile 32m x 96n (acc 48 + Bb[3][6] 72 regs -> 3
// waves/SIMD). Per 64-k body: 6 MFMA (220 matrix-cy) vs ~40 VALU inst.
// R4's 32m failure factors each fixed: B slab/XCD 2.25 MB < L2, mblk-major
// co-residency, distance-2 + setprio cover, raw s_barrier per k-triple keeps
// the 4 B-sharing waves inside L1 residency (no waitcnt drain: raw barrier).
// Epilogue: limbs accumulated exactly into LDS i64 via atomicAdd (|sum| <
// 2^36 << 2^53, double conversion exact).
// ---------------------------------------------------------------------------
__global__ __launch_bounds__(256, 3) void fused_stage1(
    const u64* __restrict__ AT0, const char* __restrict__ Bf,
    const float* __restrict__ g, char* __restrict__ Cf,
    float* __restrict__ Mean)
{
    constexpr int KI    = N_IN / 64;        // 48
    constexpr int NTILES = 192;
    constexpr int BSTEP = 2 * NTILES * 1024;  // bytes per body (2 kb)
    constexpr int KSOFF = NTILES * 1024;      // bytes per kb
    __shared__ long long hsI[128 * 32];       // 32 KB

    const int tid  = threadIdx.x;
    const int lane = tid & 63;
    const int w    = tid >> 6;
    const int col  = lane & 31;
    const int qd   = lane >> 5;
    const int wm   = w * 32;

    #pragma unroll
    for (int i = 0; i < 16; ++i) hsI[tid + i * 256] = 0;
    __syncthreads();

    // mblk-major XCD map: 64 nblk (8/XCD), 64 mblk
    const int id    = blockIdx.x;
    const int xcd   = id & 7;
    const int inner = id >> 3;
    const int nblk  = xcd * 8 + (inner >> 6);
    const int mblk  = inner & 63;
    const int m0    = mblk * 128;

    const u64* AT = AT0 + (m0 + wm + col);
    const int sh16 = qd * 16;
    const char* Bu = Bf + (size_t)nblk * 3 * 1024 + lane * 16;

    v16i acc[3];
    #pragma unroll
    for (int j = 0; j < 3; ++j)
        #pragma unroll
        for (int r = 0; r < 16; ++r) acc[j][r] = 0;

    u64 ab[3];
    v4i Bb[3][6];

    // preload bodies 0,1 (distance-2)
    #pragma unroll
    for (int s = 0; s < 2; ++s) {
        ab[s] = AT[(size_t)s * M_ROWS];
        const char* bu = Bu + (size_t)s * BSTEP;
        #pragma unroll
        for (int ks = 0; ks < 2; ++ks)
            #pragma unroll
            for (int jj = 0; jj < 3; ++jj)
                Bb[s][ks * 3 + jj] = *(const v4i*)(bu + ks * KSOFF + jj * 1024);
    }

    auto body = [&](int it, int cur, int pf) {
        const int itp = it + 2;               // clamp-free (padded buffers)
        ab[pf] = AT[(size_t)itp * M_ROWS];
        const char* bu = Bu + (size_t)itp * BSTEP;
        #pragma unroll
        for (int ks = 0; ks < 2; ++ks)
            #pragma unroll
            for (int jj = 0; jj < 3; ++jj)
                Bb[pf][ks * 3 + jj] = *(const v4i*)(bu + ks * KSOFF + jj * 1024);
        __builtin_amdgcn_s_setprio(1);
        #pragma unroll
        for (int ks = 0; ks < 2; ++ks) {
            uint32 dw = ks ? (uint32)(ab[cur] >> 32) : (uint32)ab[cur];
            v4i af = unpack16_bits(dw >> sh16);
            #pragma unroll
            for (int jj = 0; jj < 3; ++jj)
                acc[jj] = __builtin_amdgcn_mfma_i32_32x32x32_i8(
                    af, Bb[cur][ks * 3 + jj], acc[jj], 0, 0, 0);
        }
        __builtin_amdgcn_s_setprio(0);
    };

    for (int it = 0; it < KI; it += 3) {
        __builtin_amdgcn_s_barrier();         // raw: keeps waves B-in-phase
        body(it + 0, 0, 2);
        body(it + 1, 1, 0);
        body(it + 2, 2, 1);
    }

    // ---- exact limb accumulate into LDS i64 ----
    int ocol[3], lsh[3];
    #pragma unroll
    for (int jj = 0; jj < 3; ++jj) {
        int grb   = jj * 32 + col;
        int o_rel = grb / 24;
        int rem   = grb - o_rel * 24;
        int e_    = rem / 3;
        int limb  = rem - e_ * 3;
        ocol[jj]  = o_rel * 8 + e_;
        lsh[jj]   = limb * 8;
    }
    #pragma unroll
    for (int jj = 0; jj < 3; ++jj)
        #pragma unroll
        for (int reg = 0; reg < 16; ++reg) {
            int m = wm + (reg & 3) + 8 * (reg >> 2) + 4 * qd;
            atomicAdd((unsigned long long*)&hsI[m * 32 + ocol[jj]],
                      (unsigned long long)((long long)acc[jj][reg] << lsh[jj]));
        }
    __syncthreads();

    // ---- LIF: thread = (b_loc = tid>>5, o_loc = (tid>>3)&3, e = tid&7) ----
    const int b_loc = tid >> 5;
    const int oe    = tid & 31;
    const int o_loc = oe >> 3;
    const int e     = tid & 7;
    const float ge  = g[e];
    const int bg = mblk * 8 + b_loc;
    const int og = nblk * 4 + o_loc;

    const int kb_a   = og >> 5;
    const int qd_a   = (og >> 4) & 1;
    const int byte_a = og & 15;

    const double sc = 1.0 / 16777216.0;
    double v = 0.0;
    float gacc = 0.0f;
    #pragma unroll
    for (int t = 0; t < T_STEPS; ++t) {
        double h  = (double)hsI[(b_loc * 16 + t) * 32 + oe] * sc;
        double vv = v * 0.95 + h;
        int spk = (vv >= 1.0) ? 1 : 0;
        v = vv - (double)spk;
        float gs = ge * (float)spk;
        gs += __shfl_xor(gs, 1);
        gs += __shfl_xor(gs, 2);
        gs += __shfl_xor(gs, 4);
        gacc += gs;
        int cnt = spk;
        cnt += __shfl_xor(cnt, 1);
        cnt += __shfl_xor(cnt, 2);
        cnt += __shfl_xor(cnt, 4);
        if (e == 0) {
            int mp = bg * 16 + t;
            int lane_a = (mp & 31) + 32 * qd_a;
            Cf[(((size_t)kb_a * MT_ALL + (mp >> 5)) * 64 + lane_a) * 16 + byte_a]
                = (char)cnt;
        }
    }
    if (e == 0) Mean[(size_t)bg * S1 + og] = gacc * 0.0625f;
}

// ---------------------------------------------------------------------------
// Generic fused stage (stages 2/3): R6's proven frag path, 4-limb, block
// 256m x 64n, shuffle recombine epilogue. Unchanged.
// ---------------------------------------------------------------------------
template<int K, int S, int SHIFT, bool WRITEC, int NBLK, int MINW>
__global__ __launch_bounds__(256, MINW) void fused_stage(
    const char* __restrict__ Ap, const char* __restrict__ Bf,
    const float* __restrict__ g, char* __restrict__ Cf,
    float* __restrict__ Mean)
{
    constexpr int KI = K / 64;
    static_assert(KI % 2 == 0, "frag path wants even KI");
    constexpr int NT = S;
    constexpr int NS = NBLK / 8;
    __shared__ double hs[256][16];           // 32 KB

    const int tid  = threadIdx.x;
    const int lane = tid & 63;
    const int w    = tid >> 6;
    const int col  = lane & 31;
    const int qd   = lane >> 5;
    const int wm   = w * 64;

    const int id    = blockIdx.x;
    const int xcd   = id & 7;
    const int inner = id >> 3;
    const int nblk  = xcd * NS + (inner >> 5);
    const int mblk  = inner & 31;
    const int m0    = mblk * 256;

    const int nt0 = nblk * 2;
    const char* Bbase = Bf + ((size_t)nt0 * 64 + lane) * 16;

    v16i acc[2][2];
    #pragma unroll
    for (int i = 0; i < 2; ++i)
        #pragma unroll
        for (int j = 0; j < 2; ++j)
            #pragma unroll
            for (int r = 0; r < 16; ++r) acc[i][j][r] = 0;

    auto loadB = [&](int kb, int jj) -> v4i {
        return *(const v4i*)(Bbase + (size_t)kb * (NT * 1024) + jj * 1024);
    };
    const int mt0 = (m0 + wm) >> 5;
    const char* Abase = Ap + ((size_t)mt0 * 64 + lane) * 16;
    auto loadA = [&](int kb, int ii) -> v4i {
        return *(const v4i*)(Abase + (size_t)kb * (MT_ALL * 1024) + ii * 1024);
    };

    v4i Ab[2][4];
    v4i Bb[2][4];

    #pragma unroll
    for (int ks = 0; ks < 2; ++ks) {
        Ab[0][ks * 2 + 0] = loadA(ks, 0);
        Ab[0][ks * 2 + 1] = loadA(ks, 1);
        #pragma unroll
        for (int jj = 0; jj < 2; ++jj)
            Bb[0][ks * 2 + jj] = loadB(ks, jj);
    }

    auto body = [&](int it, int cur, int pf) {
        const int itp = it + 1;
        #pragma unroll
        for (int ks = 0; ks < 2; ++ks) {
            Ab[pf][ks * 2 + 0] = loadA(itp * 2 + ks, 0);
            Ab[pf][ks * 2 + 1] = loadA(itp * 2 + ks, 1);
            #pragma unroll
            for (int jj = 0; jj < 2; ++jj)
                Bb[pf][ks * 2 + jj] = loadB(itp * 2 + ks, jj);
        }
        #pragma unroll
        for (int ks = 0; ks < 2; ++ks)
            #pragma unroll
            for (int jj = 0; jj < 2; ++jj) {
                acc[0][jj] = __builtin_amdgcn_mfma_i32_32x32x32_i8(Ab[cur][ks*2+0], Bb[cur][ks*2+jj], acc[0][jj], 0,0,0);
                acc[1][jj] = __builtin_amdgcn_mfma_i32_32x32x32_i8(Ab[cur][ks*2+1], Bb[cur][ks*2+jj], acc[1][jj], 0,0,0);
            }
    };
    for (int it = 0; it < KI; it += 2) {
        body(it + 0, 0, 1);
        body(it + 1, 1, 0);
    }

    // ---- limb recombine (exact): int pair-combine then one f64 fma ----
    const double sbase = 1.0 / (double)(1ll << SHIFT);
    #pragma unroll
    for (int j = 0; j < 2; ++j) {
        const int oe = j * 8 + (col >> 2);
        #pragma unroll
        for (int i = 0; i < 2; ++i) {
            #pragma unroll
            for (int reg = 0; reg < 16; ++reg) {
                int a = acc[i][j][reg];
                int s01 = a + (__shfl_xor(a, 1) << 8);
                int s23 = __shfl_xor(s01, 2);
                double d = ((double)s01 + 65536.0 * (double)s23) * sbase;
                if ((col & 3) == 0) {
                    int m = wm + i * 32 + (reg & 3) + 8 * (reg >> 2) + 4 * qd;
                    hs[m][oe] = d;
                }
            }
        }
    }
    __syncthreads();

    const int b_loc  = tid >> 4;
    const int o_loc  = (tid >> 3) & 1;
    const int e      = tid & 7;
    const int oe     = o_loc * 8 + e;
    const float ge   = g[e];
    const int bg = mblk * 16 + b_loc;
    const int og = nblk * 2 + o_loc;

    const int kb_a   = og >> 5;
    const int qd_a   = (og >> 4) & 1;
    const int byte_a = og & 15;

    double v = 0.0;
    float gacc = 0.0f;
    #pragma unroll
    for (int t = 0; t < T_STEPS; ++t) {
        double h  = hs[b_loc * 16 + t][oe];
        double vv = v * 0.95 + h;
        int spk = (vv >= 1.0) ? 1 : 0;
        v = vv - (double)spk;
        float gs = ge * (float)spk;
        gs += __shfl_xor(gs, 1);
        gs += __shfl_xor(gs, 2);
        gs += __shfl_xor(gs, 4);
        gacc += gs;
        if (WRITEC) {
            int cnt = spk;
            cnt += __shfl_xor(cnt, 1);
            cnt += __shfl_xor(cnt, 2);
            cnt += __shfl_xor(cnt, 4);
            if (e == 0) {
                int mp = bg * 16 + t;
                int lane_a = (mp & 31) + 32 * qd_a;
                Cf[(((size_t)kb_a * MT_ALL + (mp >> 5)) * 64 + lane_a) * 16 + byte_a]
                    = (char)cnt;
            }
        }
    }
    if (e == 0) Mean[(size_t)bg * S + og] = gacc * 0.0625f;
}

// ---------------------------------------------------------------------------
// ws layout (bytes), padded for clamp-free distance-2/1 prefetch:
//   AbitsT @ 0          : 3 MB  (pad to 4 MB; A prefetch <= 3.3 MB)
//   B1f    @ 4194304    : 18 MB 3-limb (pad region 20.97 MB >= 19.5 needed)
//   B2f    @ 25165824   :  2 MB (region 3 MB >= 2.5 needed)
//   B3f    @ 28311552   :  1 MB (region 2 MB >= 1.3 needed)
//   c1f    @ 30408704   :  2 MB (region 4 MB >= 2.75 needed)
//   c2f    @ 34603008   :  2 MB (region 4 MB)   -> end 38797312 (37 MB)
// ---------------------------------------------------------------------------
extern "C" void kernel_launch(void* const* d_in, const int* in_sizes, int n_in,
                              void* d_out, int out_size, void* d_ws, size_t ws_size,
                              hipStream_t stream) {
    const float* x  = (const float*)d_in[0];
    const float* W1 = (const float*)d_in[1];
    const float* W2 = (const float*)d_in[2];
    const float* W3 = (const float*)d_in[3];
    const float* g1 = (const float*)d_in[4];
    const float* g2 = (const float*)d_in[5];
    const float* g3 = (const float*)d_in[6];
    float* out = (float*)d_out;

    char* ws = (char*)d_ws;
    u64*  AbitsT = (u64*)ws;
    char* B1f    = ws + 4194304ull;
    char* B2f    = ws + 25165824ull;
    char* B3f    = ws + 28311552ull;
    char* c1f    = ws + 30408704ull;
    char* c2f    = ws + 34603008ull;

    dim3 blk(256);

    // --- single precompute dispatch ---
    prep<<<98304 + 4608 + 512 + 256, blk, 0, stream>>>(
        x, W1, W2, W3, AbitsT, B1f, B2f, B3f);

    // --- stage 1: 3-limb, block 128m x 96n, grid 64 mblk * 64 nblk ---
    fused_stage1<<<64 * 64, blk, 0, stream>>>(AbitsT, B1f, g1, c1f, out);

    // --- stages 2/3: proven 4-limb frag path ---
    fused_stage<S1, S2, 35, true,  128, 3><<<32 * 128, blk, 0, stream>>>(
        c1f, B2f, g2, c2f, out + BATCH * S1);
    fused_stage<S2, S3, 35, false, 64, 3><<<32 * 64, blk, 0, stream>>>(
        c2f, B3f, g3, nullptr, out + BATCH * (S1 + S2));
}